// Round 11
// baseline (438.616 us; speedup 1.0000x reference)
//
#include <hip/hip_runtime.h>
#include <cstdint>
#include <cstddef>

typedef _Float16 f16;
typedef __attribute__((ext_vector_type(4))) _Float16 f16x4;
typedef __attribute__((ext_vector_type(8))) _Float16 f16x8;
typedef __attribute__((ext_vector_type(4))) float f32x4;

static constexpr int BB = 4;
static constexpr int SS = 2048;
static constexpr int EE = 1024;

static constexpr int BM = 128, BN = 128;

// async global->LDS, 16B per lane. LDS dest must be wave-uniform base + lane*16.
__device__ __forceinline__ void gload_lds16(const f16* g, f16* l) {
  __builtin_amdgcn_global_load_lds(
      (const __attribute__((address_space(1))) void*)g,
      (__attribute__((address_space(3))) void*)l, 16, 0, 0);
}

struct Frag {
  int lane, wave, wy, wx, l16, quad, quadx;
  __device__ Frag() {
    const int tid = threadIdx.x;
    lane = tid & 63; wave = tid >> 6;
    wy = wave >> 1; wx = wave & 1;
    l16 = lane & 15; quad = lane >> 4;
    quadx = quad ^ ((l16 >> 2) & 3);   // XOR-swizzled chunk select
  }
};

// Staging swizzle: LDS chunk c holds global chunk (row=c>>2, kc=(c&3)^((c>>4)&3)).
// 128x32 f16 tile = 512 chunks of 16B; 2 chunks/thread.
struct Stager {
  const f16* g[2];
  int l[2];
  __device__ void init(const f16* base, int ld, const Frag& fr) {
#pragma unroll
    for (int i = 0; i < 2; ++i) {
      const int c = fr.wave * 128 + i * 64 + fr.lane;
      const int row = c >> 2;
      const int kcs = (c & 3) ^ ((c >> 4) & 3);
      g[i] = base + (size_t)row * ld + kcs * 8;
      l[i] = c * 8;
    }
  }
  __device__ __forceinline__ void stage(int ko, f16* lds) const {
    gload_lds16(g[0] + ko, lds + l[0]);
    gload_lds16(g[1] + ko, lds + l[1]);
  }
};

// One 16-MFMA round from a staged 128x32 buffer pair
__device__ __forceinline__ void mfma_round(
    const f16* __restrict__ Ash, const f16* __restrict__ Bsh,
    f32x4 acc[4][4], const Frag& fr)
{
  f16x8 af[4], bf[4];
#pragma unroll
  for (int mi = 0; mi < 4; ++mi)
    af[mi] = *(const f16x8*)(Ash + (fr.wy * 64 + mi * 16 + fr.l16) * 32 + fr.quadx * 8);
#pragma unroll
  for (int ni = 0; ni < 4; ++ni)
    bf[ni] = *(const f16x8*)(Bsh + (fr.wx * 64 + ni * 16 + fr.l16) * 32 + fr.quadx * 8);
#pragma unroll
  for (int mi = 0; mi < 4; ++mi)
#pragma unroll
    for (int ni = 0; ni < 4; ++ni)
      acc[mi][ni] = __builtin_amdgcn_mfma_f32_16x16x32_f16(af[mi], bf[ni], acc[mi][ni], 0, 0, 0);
}

// C[m,n] = sum over k-iters [kstart, kstart+kcount) of A[m,k]*Bt[n,k] (64 k per iter)
__device__ __forceinline__ void gemm_core_k(
    const f16* __restrict__ A, const f16* __restrict__ Bt,
    int lda, int ldb, int kstart, int kcount,
    f16* __restrict__ Ash, f16* __restrict__ Bsh,   // each [2][128*32]
    f32x4 acc[4][4], const Frag& fr)
{
  Stager sa, sb;
  sa.init(A, lda, fr);
  sb.init(Bt, ldb, fr);
  for (int kt = 0; kt < kcount; ++kt) {
    const int ko = (kstart + kt) * 64;
    sa.stage(ko, Ash);       sa.stage(ko + 32, Ash + 128 * 32);
    sb.stage(ko, Bsh);       sb.stage(ko + 32, Bsh + 128 * 32);
    __syncthreads();
    mfma_round(Ash, Bsh, acc, fr);
    mfma_round(Ash + 128 * 32, Bsh + 128 * 32, acc, fr);
    __syncthreads();
  }
}

__device__ __forceinline__ void gemm_core(
    const f16* __restrict__ A, const f16* __restrict__ Bt,
    int lda, int ldb, int kOuter,
    f16* __restrict__ Ash, f16* __restrict__ Bsh,
    f32x4 acc[4][4], const Frag& fr)
{
  gemm_core_k(A, Bt, lda, ldb, 0, kOuter, Ash, Bsh, acc, fr);
}

// ---- manual grid barrier. Grid 512, 32KB LDS, <=128 VGPR -> >=4 blocks/CU capacity
// (1024 slots >= 512): co-residency guaranteed with wide margin. cnt zeroed by cast.
__device__ __forceinline__ void grid_bar(int* cnt, int nblk) {
  __syncthreads();
  if (threadIdx.x == 0) {
    __threadfence();                                   // release (device scope)
    atomicAdd(cnt, 1);
    while (atomicAdd(cnt, 0) < nblk) __builtin_amdgcn_s_sleep(2);
  }
  __syncthreads();
  __threadfence();                                     // acquire side, all threads
}

// ---------------- casts + Y zero + barrier-counter zero (one launch) ----------------
// f4 items: X cast [0, 2097152) ; weights [2097152, 2883584) ; Y zero [2883584, 4980736)
__global__ __launch_bounds__(256) void cast_all_kernel(
    const float* __restrict__ xs,
    const float* __restrict__ w0, const float* __restrict__ w1, const float* __restrict__ w2,
    f16* __restrict__ Xh, f16* __restrict__ o0, f16* __restrict__ o1, f16* __restrict__ o2,
    float* __restrict__ Y, int* __restrict__ bar)
{
  const int i = blockIdx.x * 256 + threadIdx.x;   // < 4980736 (exact grid)
  if (i < 2) bar[i] = 0;                          // reset grid-barrier counters
  if (i >= 2883584) {                             // zero Y (8M f32) for pv atomics
    const float4 z = {0.f, 0.f, 0.f, 0.f};
    ((float4*)Y)[i - 2883584] = z;
    return;
  }
  const float* src; f16* dst; int idx;
  if (i < 2097152) {
    src = xs; dst = Xh; idx = i;
  } else {
    const int j = i - 2097152;
    const int w = j >> 18;          // 262144 f4 per weight matrix
    idx = j & 262143;
    src = (w == 0) ? w0 : (w == 1) ? w1 : w2;
    dst = (w == 0) ? o0 : (w == 1) ? o1 : o2;
  }
  const float4 f = ((const float4*)src)[idx];
  f16x4 h;
  h.x = (f16)f.x; h.y = (f16)f.y; h.z = (f16)f.z; h.w = (f16)f.w;
  ((f16x4*)dst)[idx] = h;
}

// ---------------- merged projections (round-0 best-measured version) ----------------
// blocks [0,512) = fused QK item, [512,1024) = V^T item
__global__ __launch_bounds__(256, 2) void proj_kernel(
    const f16* __restrict__ X,
    const f16* __restrict__ Wq, const f16* __restrict__ Wk, const f16* __restrict__ Wv,
    const float* __restrict__ bq, const float* __restrict__ bk, const float* __restrict__ bv,
    f16* __restrict__ Qh, f16* __restrict__ Kh, f16* __restrict__ Vt)
{
  __shared__ __align__(16) f16 smem[3][2][BM * 32];   // 48 KB
  Frag fr;
  const int t = blockIdx.x;
  if (t < 512) {
    const int row0 = (t & 63) * BM, col0 = (t >> 6) * BN;
    Stager sa, sw0, sw1;
    sa.init(X + (size_t)row0 * EE, EE, fr);
    sw0.init(Wq + (size_t)col0 * EE, EE, fr);
    sw1.init(Wk + (size_t)col0 * EE, EE, fr);

    f32x4 acc[2][4][4] = {};

    for (int kt = 0; kt < EE / 64; ++kt) {
      const int ko = kt * 64;
      sa.stage(ko, smem[0][0]);   sa.stage(ko + 32, smem[0][1]);
      sw0.stage(ko, smem[1][0]);  sw0.stage(ko + 32, smem[1][1]);
      sw1.stage(ko, smem[2][0]);  sw1.stage(ko + 32, smem[2][1]);
      __syncthreads();
#pragma unroll
      for (int h = 0; h < 2; ++h) {
        f16x8 af[4];
#pragma unroll
        for (int mi = 0; mi < 4; ++mi)
          af[mi] = *(const f16x8*)(smem[0][h] + (fr.wy * 64 + mi * 16 + fr.l16) * 32 + fr.quadx * 8);
#pragma unroll
        for (int z = 0; z < 2; ++z) {
          f16x8 bf[4];
#pragma unroll
          for (int ni = 0; ni < 4; ++ni)
            bf[ni] = *(const f16x8*)(smem[1 + z][h] + (fr.wx * 64 + ni * 16 + fr.l16) * 32 + fr.quadx * 8);
#pragma unroll
          for (int mi = 0; mi < 4; ++mi)
#pragma unroll
            for (int ni = 0; ni < 4; ++ni)
              acc[z][mi][ni] = __builtin_amdgcn_mfma_f32_16x16x32_f16(af[mi], bf[ni], acc[z][mi][ni], 0, 0, 0);
        }
      }
      __syncthreads();
    }

#pragma unroll
    for (int z = 0; z < 2; ++z) {
      const float* bias = (z == 0) ? bq : bk;
      f16* out = (z == 0) ? Qh : Kh;
#pragma unroll
      for (int ni = 0; ni < 4; ++ni) {
        const int c = col0 + fr.wx * 64 + ni * 16 + fr.l16;
        const float bv2 = bias[c];
#pragma unroll
        for (int mi = 0; mi < 4; ++mi) {
          const int r = row0 + fr.wy * 64 + mi * 16 + fr.quad * 4;
#pragma unroll
          for (int i = 0; i < 4; ++i)
            out[(size_t)(r + i) * EE + c] = (f16)(acc[z][mi][ni][i] + bv2);
        }
      }
    }
  } else {
    const int u = t - 512;
    const int row0 = (u & 7) * BM;        // e
    const int sg0 = (u >> 3) * BN;        // global s in [0, BB*SS)
    const int b = sg0 / SS, s0 = sg0 % SS;
    f32x4 acc[4][4] = {};
    gemm_core(Wv + (size_t)row0 * EE, X + (size_t)sg0 * EE, EE, EE, EE / 64,
              smem[0][0], smem[1][0], acc, fr);
    f16* out = Vt + (size_t)b * EE * SS;
#pragma unroll
    for (int ni = 0; ni < 4; ++ni) {
      const int c = s0 + fr.wx * 64 + ni * 16 + fr.l16;
#pragma unroll
      for (int mi = 0; mi < 4; ++mi) {
        const int r = row0 + fr.wy * 64 + mi * 16 + fr.quad * 4;
#pragma unroll
        for (int i = 0; i < 4; ++i)
          out[(size_t)(r + i) * SS + c] = (f16)(acc[mi][ni][i] + bv[r + i]);
      }
    }
  }
}

// ---------------- fused attention: scores -> gridbar -> softmax -> gridbar -> PV ----------------
// Grid 512, 256 threads, 32KB LDS (>=4 blocks/CU capacity -> co-residency safe margin).
// Phase S: score item t; blocks t<32 also handle item 512+t (544 = 4*136 tri-tiles total).
// Phase M: wave-parallel softmax, 4 rows/wave: 512*4 waves * 4 rows = 8192 rows exact.
// Phase P: uniform 17-iter K-split PV (hi tiles atomicAdd onto zeroed Y, lo tiles plain).
__device__ __forceinline__ void score_tile(
    const f16* __restrict__ Q, const f16* __restrict__ Kh, f16* __restrict__ Sc,
    int item, f16* Ash, f16* Bsh, const Frag& fr)
{
  const int b = item / 136, tt = item - b * 136;
  int qt = 0;
  while ((qt + 1) * (qt + 2) / 2 <= tt) ++qt;
  const int kt = tt - qt * (qt + 1) / 2;
  const f16* A  = Q  + (size_t)b * SS * EE + (size_t)qt * BM * EE;
  const f16* Bp = Kh + (size_t)b * SS * EE + (size_t)kt * BN * EE;
  f16* out = Sc + (size_t)b * SS * SS;
  f32x4 acc[4][4] = {};
  gemm_core(A, Bp, EE, EE, EE / 64, Ash, Bsh, acc, fr);
  const float scale = 0.03125f;   // 1/sqrt(1024)
#pragma unroll
  for (int ni = 0; ni < 4; ++ni) {
    const int c = kt * BN + fr.wx * 64 + ni * 16 + fr.l16;
#pragma unroll
    for (int mi = 0; mi < 4; ++mi) {
      const int r = qt * BM + fr.wy * 64 + mi * 16 + fr.quad * 4;
#pragma unroll
      for (int i = 0; i < 4; ++i)
        out[(size_t)(r + i) * SS + c] = (f16)(acc[mi][ni][i] * scale);
    }
  }
}

__global__ __launch_bounds__(256) void attn_kernel(
    const f16* __restrict__ Q, const f16* __restrict__ Kh, f16* __restrict__ Sc,
    const f16* __restrict__ Vt, float* __restrict__ Y, int* __restrict__ bar)
{
  __shared__ __align__(16) f16 Ash[2][BM * 32];
  __shared__ __align__(16) f16 Bsh[2][BN * 32];
  Frag fr;
  const int t = blockIdx.x;

  // ---------- phase S: scores (blocks 0..31 take a second tile) ----------
  score_tile(Q, Kh, Sc, t, Ash[0], Bsh[0], fr);
  if (t < 32) score_tile(Q, Kh, Sc, 512 + t, Ash[0], Bsh[0], fr);

  grid_bar(&bar[0], 512);

  // ---------- phase M: softmax (wave-local, no LDS); 8192 rows exact ----------
  {
    const int gw = t * 4 + fr.wave;   // global wave id in [0, 2048)
#pragma unroll
    for (int j = 0; j < 4; ++j) {
      const int r = gw * 4 + j;       // row in [0, 8192)
      const int b = r >> 11, q = r & 2047;
      f16* row = Sc + (size_t)b * SS * SS + (size_t)q * SS;
      const int n = q + 1;
      const int kend = ((q >> 7) + 1) << 7;   // PV reads up to this 128-boundary
      float v[4][8];
      float m = -1e30f;
#pragma unroll
      for (int c = 0; c < 4; ++c) {
        const int base = c * 512 + fr.lane * 8;
        const f16x8 h = *(const f16x8*)(row + base);
#pragma unroll
        for (int e = 0; e < 8; ++e) {
          v[c][e] = (base + e < n) ? (float)h[e] : -1e30f;
          m = fmaxf(m, v[c][e]);
        }
      }
#pragma unroll
      for (int off = 32; off > 0; off >>= 1) m = fmaxf(m, __shfl_xor(m, off));
      float s = 0.f;
#pragma unroll
      for (int c = 0; c < 4; ++c)
#pragma unroll
        for (int e = 0; e < 8; ++e) {
          const int base = c * 512 + fr.lane * 8;
          v[c][e] = (base + e < n) ? __expf(v[c][e] - m) : 0.f;
          s += v[c][e];
        }
#pragma unroll
      for (int off = 32; off > 0; off >>= 1) s += __shfl_xor(s, off);
      const float inv = 1.f / s;
#pragma unroll
      for (int c = 0; c < 4; ++c) {
        const int base = c * 512 + fr.lane * 8;
        if (base < kend) {
          f16x8 h;
#pragma unroll
          for (int e = 0; e < 8; ++e) h[e] = (f16)(v[c][e] * inv);
          *(f16x8*)(row + base) = h;
        }
      }
    }
  }

  grid_bar(&bar[1], 512);

  // ---------- phase P: PV (uniform 17-iter K-split; hi tiles atomic, lo plain) ----------
  {
    const int u = t & 255;
    const int qh = u & 7, et = (u >> 3) & 7, b = u >> 6;
    const int seg = t >> 8;
    const int qhi = 15 - qh;
    const int Uhi = (qhi + 1) * 2;
    const int Ulo = (qh + 1) * 2;
    const f16* Pb = Sc + (size_t)b * SS * SS;
    const f16* Bp = Vt + (size_t)b * EE * SS + (size_t)et * BN * SS;
    float* out = Y + (size_t)b * SS * EE;

    if (seg == 0) {
      f32x4 acc[4][4] = {};
      gemm_core_k(Pb + (size_t)qhi * BM * SS, Bp, SS, SS, 0, 17, Ash[0], Bsh[0], acc, fr);
#pragma unroll
      for (int ni = 0; ni < 4; ++ni) {
        const int c = et * BN + fr.wx * 64 + ni * 16 + fr.l16;
#pragma unroll
        for (int mi = 0; mi < 4; ++mi) {
          const int r = qhi * BM + fr.wy * 64 + mi * 16 + fr.quad * 4;
#pragma unroll
          for (int i = 0; i < 4; ++i)
            atomicAdd(&out[(size_t)(r + i) * EE + c], acc[mi][ni][i]);
        }
      }
    } else {
      {
        f32x4 acc[4][4] = {};
        gemm_core_k(Pb + (size_t)qhi * BM * SS, Bp, SS, SS, 17, Uhi - 17, Ash[0], Bsh[0], acc, fr);
#pragma unroll
        for (int ni = 0; ni < 4; ++ni) {
          const int c = et * BN + fr.wx * 64 + ni * 16 + fr.l16;
#pragma unroll
          for (int mi = 0; mi < 4; ++mi) {
            const int r = qhi * BM + fr.wy * 64 + mi * 16 + fr.quad * 4;
#pragma unroll
            for (int i = 0; i < 4; ++i)
              atomicAdd(&out[(size_t)(r + i) * EE + c], acc[mi][ni][i]);
          }
        }
      }
      {
        f32x4 acc[4][4] = {};
        gemm_core_k(Pb + (size_t)qh * BM * SS, Bp, SS, SS, 0, Ulo, Ash[0], Bsh[0], acc, fr);
#pragma unroll
        for (int ni = 0; ni < 4; ++ni) {
          const int c = et * BN + fr.wx * 64 + ni * 16 + fr.l16;
#pragma unroll
          for (int mi = 0; mi < 4; ++mi) {
            const int r = qh * BM + fr.wy * 64 + mi * 16 + fr.quad * 4;
#pragma unroll
            for (int i = 0; i < 4; ++i)
              out[(size_t)(r + i) * EE + c] = acc[mi][ni][i];
          }
        }
      }
    }
  }
}

extern "C" void kernel_launch(void* const* d_in, const int* in_sizes, int n_in,
                              void* d_out, int out_size, void* d_ws, size_t ws_size,
                              hipStream_t stream)
{
  const float* xs  = (const float*)d_in[0];
  const float* WQw = (const float*)d_in[1];
  const float* WQb = (const float*)d_in[2];
  const float* WKw = (const float*)d_in[3];
  const float* WKb = (const float*)d_in[4];
  const float* WVw = (const float*)d_in[5];
  const float* WVb = (const float*)d_in[6];

  const size_t ME = (size_t)BB * SS * EE;   // 8M tokens*dim
  const size_t WE = (size_t)EE * EE;        // 1M weight elems

  f16* Xh = (f16*)d_ws;
  f16* Wq = Xh + ME;
  f16* Wk = Wq + WE;
  f16* Wv = Wk + WE;
  f16* Qh = Wv + WE;
  f16* Kh = Qh + ME;
  f16* Vt = Kh + ME;
  f16* Sc = Vt + ME;                         // BB*SS*SS f16 = 32 MiB
  int* bar = (int*)(Sc + (size_t)BB * SS * SS);   // 2 grid-barrier counters

  // 1) casts + Y zero + barrier reset: 4980736 f4 items -> 19456 blocks exact
  cast_all_kernel<<<dim3(19456), 256, 0, stream>>>(
      xs, WQw, WKw, WVw, Xh, Wq, Wk, Wv, (float*)d_out, bar);

  // 2) projections (merged): 512 QK items + 512 VT items
  proj_kernel<<<dim3(1024), 256, 0, stream>>>(
      Xh, Wq, Wk, Wv, WQb, WKb, WVb, Qh, Kh, Vt);

  // 3) fused scores -> softmax -> PV (one dispatch, two internal grid barriers)
  attn_kernel<<<dim3(512), 256, 0, stream>>>(
      Qh, Kh, Sc, Vt, (float*)d_out, bar);
}

// Round 12
// 261.998 us; speedup vs baseline: 1.6741x; 1.6741x over previous
//
#include <hip/hip_runtime.h>
#include <cstdint>
#include <cstddef>

typedef _Float16 f16;
typedef __attribute__((ext_vector_type(4))) _Float16 f16x4;
typedef __attribute__((ext_vector_type(8))) _Float16 f16x8;
typedef __attribute__((ext_vector_type(4))) float f32x4;

static constexpr int BB = 4;
static constexpr int SS = 2048;
static constexpr int EE = 1024;

static constexpr int BM = 128, BN = 128;

// async global->LDS, 16B per lane. LDS dest must be wave-uniform base + lane*16.
__device__ __forceinline__ void gload_lds16(const f16* g, f16* l) {
  __builtin_amdgcn_global_load_lds(
      (const __attribute__((address_space(1))) void*)g,
      (__attribute__((address_space(3))) void*)l, 16, 0, 0);
}

struct Frag {
  int lane, wave, wy, wx, l16, quad, quadx;
  __device__ Frag() {
    const int tid = threadIdx.x;
    lane = tid & 63; wave = tid >> 6;
    wy = wave >> 1; wx = wave & 1;
    l16 = lane & 15; quad = lane >> 4;
    quadx = quad ^ ((l16 >> 2) & 3);   // XOR-swizzled chunk select
  }
};

// Staging swizzle: LDS chunk c holds global chunk (row=c>>2, kc=(c&3)^((c>>4)&3)).
// 128x32 f16 tile = 512 chunks of 16B; 2 chunks/thread.
struct Stager {
  const f16* g[2];
  int l[2];
  __device__ void init(const f16* base, int ld, const Frag& fr) {
#pragma unroll
    for (int i = 0; i < 2; ++i) {
      const int c = fr.wave * 128 + i * 64 + fr.lane;
      const int row = c >> 2;
      const int kcs = (c & 3) ^ ((c >> 4) & 3);
      g[i] = base + (size_t)row * ld + kcs * 8;
      l[i] = c * 8;
    }
  }
  __device__ __forceinline__ void stage(int ko, f16* lds) const {
    gload_lds16(g[0] + ko, lds + l[0]);
    gload_lds16(g[1] + ko, lds + l[1]);
  }
};

// One 16-MFMA round from a staged 128x32 buffer pair
__device__ __forceinline__ void mfma_round(
    const f16* __restrict__ Ash, const f16* __restrict__ Bsh,
    f32x4 acc[4][4], const Frag& fr)
{
  f16x8 af[4], bf[4];
#pragma unroll
  for (int mi = 0; mi < 4; ++mi)
    af[mi] = *(const f16x8*)(Ash + (fr.wy * 64 + mi * 16 + fr.l16) * 32 + fr.quadx * 8);
#pragma unroll
  for (int ni = 0; ni < 4; ++ni)
    bf[ni] = *(const f16x8*)(Bsh + (fr.wx * 64 + ni * 16 + fr.l16) * 32 + fr.quadx * 8);
#pragma unroll
  for (int mi = 0; mi < 4; ++mi)
#pragma unroll
    for (int ni = 0; ni < 4; ++ni)
      acc[mi][ni] = __builtin_amdgcn_mfma_f32_16x16x32_f16(af[mi], bf[ni], acc[mi][ni], 0, 0, 0);
}

// C[m,n] = sum_k A[m,k]*Bt[n,k]; 2x(128x32) staged per barrier -> 32 MFMA/barrier
__device__ __forceinline__ void gemm_core(
    const f16* __restrict__ A, const f16* __restrict__ Bt,
    int lda, int ldb, int kOuter,
    f16* __restrict__ Ash, f16* __restrict__ Bsh,   // each [2][128*32]
    f32x4 acc[4][4], const Frag& fr)
{
  Stager sa, sb;
  sa.init(A, lda, fr);
  sb.init(Bt, ldb, fr);
  for (int kt = 0; kt < kOuter; ++kt) {
    const int ko = kt * 64;
    sa.stage(ko, Ash);       sa.stage(ko + 32, Ash + 128 * 32);
    sb.stage(ko, Bsh);       sb.stage(ko + 32, Bsh + 128 * 32);
    __syncthreads();
    mfma_round(Ash, Bsh, acc, fr);
    mfma_round(Ash + 128 * 32, Bsh + 128 * 32, acc, fr);
    __syncthreads();
  }
}

// ---------------- single cast launch: X (2M f4) then Wq/Wk/Wv (256K f4 each) ----------------
__global__ __launch_bounds__(256) void cast_all_kernel(
    const float* __restrict__ xs,
    const float* __restrict__ w0, const float* __restrict__ w1, const float* __restrict__ w2,
    f16* __restrict__ Xh, f16* __restrict__ o0, f16* __restrict__ o1, f16* __restrict__ o2)
{
  const int i = blockIdx.x * 256 + threadIdx.x;   // f4 index < 2883584 (exact grid)
  const float* src; f16* dst; int idx;
  if (i < 2097152) {
    src = xs; dst = Xh; idx = i;
  } else {
    const int j = i - 2097152;
    const int w = j >> 18;          // 262144 f4 per weight matrix
    idx = j & 262143;
    src = (w == 0) ? w0 : (w == 1) ? w1 : w2;
    dst = (w == 0) ? o0 : (w == 1) ? o1 : o2;
  }
  const float4 f = ((const float4*)src)[idx];
  f16x4 h;
  h.x = (f16)f.x; h.y = (f16)f.y; h.z = (f16)f.z; h.w = (f16)f.w;
  ((f16x4*)dst)[idx] = h;
}

// ---------------- merged projections: blocks [0,512) = fused QK item, [512,1024) = V^T item ----------------
// QK: per item stage X-tile + Wq/Wk tiles (2x32 buffers), 64 MFMA/barrier -> Qh, Kh (+bias, f16)
// VT: Vt[e][s] = sum_h Wv[e,h] X[s,h] + bv[e]  (BT-GEMM, writes V transposed directly)
__global__ __launch_bounds__(256, 2) void proj_kernel(
    const f16* __restrict__ X,
    const f16* __restrict__ Wq, const f16* __restrict__ Wk, const f16* __restrict__ Wv,
    const float* __restrict__ bq, const float* __restrict__ bk, const float* __restrict__ bv,
    f16* __restrict__ Qh, f16* __restrict__ Kh, f16* __restrict__ Vt)
{
  __shared__ __align__(16) f16 smem[3][2][BM * 32];   // 48 KB
  Frag fr;
  const int t = blockIdx.x;
  if (t < 512) {
    const int row0 = (t & 63) * BM, col0 = (t >> 6) * BN;
    Stager sa, sw0, sw1;
    sa.init(X + (size_t)row0 * EE, EE, fr);
    sw0.init(Wq + (size_t)col0 * EE, EE, fr);
    sw1.init(Wk + (size_t)col0 * EE, EE, fr);

    f32x4 acc[2][4][4] = {};

    for (int kt = 0; kt < EE / 64; ++kt) {
      const int ko = kt * 64;
      sa.stage(ko, smem[0][0]);   sa.stage(ko + 32, smem[0][1]);
      sw0.stage(ko, smem[1][0]);  sw0.stage(ko + 32, smem[1][1]);
      sw1.stage(ko, smem[2][0]);  sw1.stage(ko + 32, smem[2][1]);
      __syncthreads();
#pragma unroll
      for (int h = 0; h < 2; ++h) {
        f16x8 af[4];
#pragma unroll
        for (int mi = 0; mi < 4; ++mi)
          af[mi] = *(const f16x8*)(smem[0][h] + (fr.wy * 64 + mi * 16 + fr.l16) * 32 + fr.quadx * 8);
#pragma unroll
        for (int z = 0; z < 2; ++z) {
          f16x8 bf[4];
#pragma unroll
          for (int ni = 0; ni < 4; ++ni)
            bf[ni] = *(const f16x8*)(smem[1 + z][h] + (fr.wx * 64 + ni * 16 + fr.l16) * 32 + fr.quadx * 8);
#pragma unroll
          for (int mi = 0; mi < 4; ++mi)
#pragma unroll
            for (int ni = 0; ni < 4; ++ni)
              acc[z][mi][ni] = __builtin_amdgcn_mfma_f32_16x16x32_f16(af[mi], bf[ni], acc[z][mi][ni], 0, 0, 0);
        }
      }
      __syncthreads();
    }

#pragma unroll
    for (int z = 0; z < 2; ++z) {
      const float* bias = (z == 0) ? bq : bk;
      f16* out = (z == 0) ? Qh : Kh;
#pragma unroll
      for (int ni = 0; ni < 4; ++ni) {
        const int c = col0 + fr.wx * 64 + ni * 16 + fr.l16;
        const float bv2 = bias[c];
#pragma unroll
        for (int mi = 0; mi < 4; ++mi) {
          const int r = row0 + fr.wy * 64 + mi * 16 + fr.quad * 4;
#pragma unroll
          for (int i = 0; i < 4; ++i)
            out[(size_t)(r + i) * EE + c] = (f16)(acc[z][mi][ni][i] + bv2);
        }
      }
    }
  } else {
    const int u = t - 512;
    const int row0 = (u & 7) * BM;        // e
    const int sg0 = (u >> 3) * BN;        // global s in [0, BB*SS)
    const int b = sg0 / SS, s0 = sg0 % SS;
    f32x4 acc[4][4] = {};
    gemm_core(Wv + (size_t)row0 * EE, X + (size_t)sg0 * EE, EE, EE, EE / 64,
              smem[0][0], smem[1][0], acc, fr);
    f16* out = Vt + (size_t)b * EE * SS;
#pragma unroll
    for (int ni = 0; ni < 4; ++ni) {
      const int c = s0 + fr.wx * 64 + ni * 16 + fr.l16;
#pragma unroll
      for (int mi = 0; mi < 4; ++mi) {
        const int r = row0 + fr.wy * 64 + mi * 16 + fr.quad * 4;
#pragma unroll
        for (int i = 0; i < 4; ++i)
          out[(size_t)(r + i) * SS + c] = (f16)(acc[mi][ni][i] + bv[r + i]);
      }
    }
  }
}

// ---------------- scores: Sc[q,k] = (Q[q,:] . K[k,:]) / 32, lower-tri tiles only ----------------
__global__ __launch_bounds__(256) void scores_kernel(
    const f16* __restrict__ Q, const f16* __restrict__ Kh, f16* __restrict__ Sc)
{
  __shared__ __align__(16) f16 Ash[2][BM * 32];
  __shared__ __align__(16) f16 Bsh[2][BN * 32];
  const int t = blockIdx.x, b = blockIdx.z;
  int qt = 0;
  while ((qt + 1) * (qt + 2) / 2 <= t) ++qt;
  const int kt = t - qt * (qt + 1) / 2;
  const f16* A  = Q  + (size_t)b * SS * EE + (size_t)qt * BM * EE;
  const f16* Bp = Kh + (size_t)b * SS * EE + (size_t)kt * BN * EE;
  f16* out = Sc + (size_t)b * SS * SS;
  Frag fr;
  f32x4 acc[4][4] = {};
  gemm_core(A, Bp, EE, EE, EE / 64, Ash[0], Bsh[0], acc, fr);
  const float scale = 0.03125f;   // 1/sqrt(1024)
#pragma unroll
  for (int ni = 0; ni < 4; ++ni) {
    const int c = kt * BN + fr.wx * 64 + ni * 16 + fr.l16;
#pragma unroll
    for (int mi = 0; mi < 4; ++mi) {
      const int r = qt * BM + fr.wy * 64 + mi * 16 + fr.quad * 4;
#pragma unroll
      for (int i = 0; i < 4; ++i)
        out[(size_t)(r + i) * SS + c] = (f16)(acc[mi][ni][i] * scale);
    }
  }
}

// ---------------- causal softmax, wave-parallel: 512 blocks x 4 waves x 4 rows = 8192 rows ----
// (verified correct as phase M of round-11's fused kernel; shuffle-only, no LDS/barriers)
__global__ __launch_bounds__(256) void softmax2_kernel(f16* __restrict__ Sc)
{
  const int tid = threadIdx.x;
  const int lane = tid & 63, wave = tid >> 6;
  const int gw = blockIdx.x * 4 + wave;   // global wave id in [0, 2048)
#pragma unroll
  for (int j = 0; j < 4; ++j) {
    const int r = gw * 4 + j;             // row in [0, 8192)
    const int b = r >> 11, q = r & 2047;
    f16* row = Sc + (size_t)b * SS * SS + (size_t)q * SS;
    const int n = q + 1;
    const int kend = ((q >> 7) + 1) << 7; // PV reads up to this 128-boundary
    float v[4][8];
    float m = -1e30f;
#pragma unroll
    for (int c = 0; c < 4; ++c) {
      const int base = c * 512 + lane * 8;
      const f16x8 h = *(const f16x8*)(row + base);
#pragma unroll
      for (int e = 0; e < 8; ++e) {
        v[c][e] = (base + e < n) ? (float)h[e] : -1e30f;
        m = fmaxf(m, v[c][e]);
      }
    }
#pragma unroll
    for (int off = 32; off > 0; off >>= 1) m = fmaxf(m, __shfl_xor(m, off));
    float s = 0.f;
#pragma unroll
    for (int c = 0; c < 4; ++c)
#pragma unroll
      for (int e = 0; e < 8; ++e) {
        const int base = c * 512 + lane * 8;
        v[c][e] = (base + e < n) ? __expf(v[c][e] - m) : 0.f;
        s += v[c][e];
      }
#pragma unroll
    for (int off = 32; off > 0; off >>= 1) s += __shfl_xor(s, off);
    const float inv = 1.f / s;
#pragma unroll
    for (int c = 0; c < 4; ++c) {
      const int base = c * 512 + lane * 8;
      if (base < kend) {
        f16x8 h;
#pragma unroll
        for (int e = 0; e < 8; ++e) h[e] = (f16)(v[c][e] * inv);
        *(f16x8*)(row + base) = h;
      }
    }
  }
}

// ---------------- PV: Y[q,e] = sum_{k<=q} P[q,k] * Vt[e,k], fp32 out ----------------
// Flat 512-block grid with complementary-pair remap: block t and t+256 map to
// qt=15-qh and qt=qh (same et,b) -> uniform per-CU K-tile load.
__global__ __launch_bounds__(256) void pv_kernel(
    const f16* __restrict__ P, const f16* __restrict__ Vt, float* __restrict__ Y)
{
  __shared__ __align__(16) f16 Ash[2][BM * 32];
  __shared__ __align__(16) f16 Bsh[2][BN * 32];
  const int t = blockIdx.x;
  const int u = t & 255;
  const int qh = u & 7, et = (u >> 3) & 7, b = u >> 6;
  const int qt = (t < 256) ? (15 - qh) : qh;
  const f16* A  = P  + (size_t)b * SS * SS + (size_t)qt * BM * SS;
  const f16* Bp = Vt + (size_t)b * EE * SS + (size_t)et * BN * SS;
  float* out = Y + (size_t)b * SS * EE;
  Frag fr;
  f32x4 acc[4][4] = {};
  gemm_core(A, Bp, SS, SS, (qt + 1) * 2, Ash[0], Bsh[0], acc, fr);
#pragma unroll
  for (int ni = 0; ni < 4; ++ni) {
    const int c = et * BN + fr.wx * 64 + ni * 16 + fr.l16;
#pragma unroll
    for (int mi = 0; mi < 4; ++mi) {
      const int r = qt * BM + fr.wy * 64 + mi * 16 + fr.quad * 4;
#pragma unroll
      for (int i = 0; i < 4; ++i)
        out[(size_t)(r + i) * EE + c] = acc[mi][ni][i];
    }
  }
}

extern "C" void kernel_launch(void* const* d_in, const int* in_sizes, int n_in,
                              void* d_out, int out_size, void* d_ws, size_t ws_size,
                              hipStream_t stream)
{
  const float* xs  = (const float*)d_in[0];
  const float* WQw = (const float*)d_in[1];
  const float* WQb = (const float*)d_in[2];
  const float* WKw = (const float*)d_in[3];
  const float* WKb = (const float*)d_in[4];
  const float* WVw = (const float*)d_in[5];
  const float* WVb = (const float*)d_in[6];

  const size_t ME = (size_t)BB * SS * EE;   // 8M tokens*dim
  const size_t WE = (size_t)EE * EE;        // 1M weight elems

  f16* Xh = (f16*)d_ws;
  f16* Wq = Xh + ME;
  f16* Wk = Wq + WE;
  f16* Wv = Wk + WE;
  f16* Qh = Wv + WE;
  f16* Kh = Qh + ME;
  f16* Vt = Kh + ME;
  f16* Sc = Vt + ME;   // BB*SS*SS f16 = 32 MiB

  // 1) casts (one launch): (8M + 3*1M)/4 = 2883584 f4 -> 11264 blocks exact
  cast_all_kernel<<<dim3(11264), 256, 0, stream>>>(
      xs, WQw, WKw, WVw, Xh, Wq, Wk, Wv);

  // 2) projections (one launch): 512 QK items + 512 VT items
  proj_kernel<<<dim3(1024), 256, 0, stream>>>(
      Xh, Wq, Wk, Wv, WQb, WKb, WVb, Qh, Kh, Vt);

  // 3) scores (lower-tri tiles)
  const int nTri = (SS / BM) * (SS / BM + 1) / 2;   // 136
  scores_kernel<<<dim3(nTri, 1, BB), 256, 0, stream>>>(Qh, Kh, Sc);

  // 4) softmax (wave-parallel, 512 blocks)
  softmax2_kernel<<<dim3(512), 256, 0, stream>>>(Sc);

  // 5) PV
  pv_kernel<<<dim3(512), 256, 0, stream>>>(Sc, Vt, (float*)d_out);
}